// Round 4
// baseline (8377.521 us; speedup 1.0000x reference)
//
#include <hip/hip_runtime.h>
#include <hip/hip_bf16.h>

#define NB 32
#define NT 512
#define NH 1024
#define G3 3072
#define NWG 128
#define LDS_BLOB 98304
#define LDS_PART 16384
#define LDS_HPF  8192
#define LDS_HLOC 2048
#define PK_LDS (LDS_BLOB + LDS_PART + LDS_HPF + LDS_HLOC)

typedef __attribute__((ext_vector_type(8))) short short8;
typedef __attribute__((ext_vector_type(4))) float f32x4;
typedef __attribute__((ext_vector_type(4))) unsigned short us4;
typedef unsigned long long u64;

static __device__ __forceinline__ unsigned short f2bf(float f) {
    union { float f; unsigned u; } v; v.f = f;
    if ((v.u & 0x7fffffffu) > 0x7f800000u) return (unsigned short)((v.u >> 16) | 0x0040u);
    unsigned u = v.u + 0x7fffu + ((v.u >> 16) & 1u);
    return (unsigned short)(u >> 16);
}

// coherent (LLC point) 16B load as two relaxed agent-scope u64 atomics
static __device__ __forceinline__ short8 coh_load16(const u64* p) {
    u64 lo = __hip_atomic_load(p,     __ATOMIC_RELAXED, __HIP_MEMORY_SCOPE_AGENT);
    u64 hi = __hip_atomic_load(p + 1, __ATOMIC_RELAXED, __HIP_MEMORY_SCOPE_AGENT);
    union { u64 u[2]; short8 s; } r;
    r.u[0] = lo; r.u[1] = hi;
    return r.s;
}
static __device__ __forceinline__ void coh_store8(u64* p, u64 v) {
    __hip_atomic_store(p, v, __ATOMIC_RELAXED, __HIP_MEMORY_SCOPE_AGENT);
}

// ---------------- f32 -> bf16 conversion (vectorized) ----------------
__global__ __launch_bounds__(256) void cvt_bf16_v4(const float4* __restrict__ src,
                                                   us4* __restrict__ dst, int n4) {
    for (int i = blockIdx.x * 256 + threadIdx.x; i < n4; i += gridDim.x * 256) {
        float4 v = src[i];
        us4 o;
        o.x = f2bf(v.x); o.y = f2bf(v.y); o.z = f2bf(v.z); o.w = f2bf(v.w);
        dst[i] = o;
    }
}

// ---------------- x [B][T][D] f32 -> xt [T][B][D] bf16 ----------------
__global__ __launch_bounds__(256) void txp_x(const float4* __restrict__ x, us4* __restrict__ xt) {
    const int total = NT * NB * 256;   // in float4 units
    for (int i = blockIdx.x * 256 + threadIdx.x; i < total; i += gridDim.x * 256) {
        int b = i / (NT * 256);
        int rem = i - b * (NT * 256);
        int t = rem >> 8;
        int d4 = rem & 255;
        float4 v = x[i];
        us4 o;
        o.x = f2bf(v.x); o.y = f2bf(v.y); o.z = f2bf(v.z); o.w = f2bf(v.w);
        xt[((size_t)t * NB + b) * 256 + d4] = o;
    }
}

// ---------------- init hidden bf16 shadows ----------------
__global__ __launch_bounds__(256) void init_h(const float* __restrict__ hid,
                                              unsigned short* __restrict__ h0b,
                                              unsigned short* __restrict__ h1b) {
    int i = blockIdx.x * 256 + threadIdx.x;   // grid covers exactly NB*NH
    h0b[i] = f2bf(hid[i]);
    h1b[i] = f2bf(hid[NB * NH + i]);
}

// ---------------- persistent 2-layer GRU, fence-free coherent exchange ----------------
__global__ __launch_bounds__(256, 1) void gru_persistent(
    const unsigned short* __restrict__ xt,      // [T][B][1024] bf16
    unsigned short* __restrict__ y0b,           // [T][B][1024] bf16 (coherent)
    const unsigned short* __restrict__ wih0, const unsigned short* __restrict__ whh0,
    const unsigned short* __restrict__ wih1, const unsigned short* __restrict__ whh1,
    const float* __restrict__ bih0, const float* __restrict__ bhh0,
    const float* __restrict__ bih1, const float* __restrict__ bhh1,
    const float* __restrict__ hid,              // [2][B][1024] f32
    unsigned short* __restrict__ hb00, unsigned short* __restrict__ hb01,
    unsigned short* __restrict__ hb10, unsigned short* __restrict__ hb11,
    float* __restrict__ out,                    // y1 [B][T][1024] f32, then h [2][B][1024]
    int* __restrict__ flags)                    // fl0 = flags, fl1 = flags + 64*32
{
    extern __shared__ char lds[];
    short* blob = (short*)lds;                               // w_hh fragment blobs
    float* part = (float*)(lds + LDS_BLOB);                  // per-wave partials
    float* hpf  = (float*)(lds + LDS_BLOB + LDS_PART);       // reduced pre-acts [4][32][16]
    float* hloc = (float*)(lds + LDS_BLOB + LDS_PART + LDS_HPF); // f32 h_prev [32][16]

    const int tid  = threadIdx.x;
    const int lane = tid & 63;
    const int wv   = tid >> 6;      // 0..3
    const int kh   = wv & 1;        // K-half
    const int mt   = wv >> 1;       // M-tile (batch 0-15 / 16-31)
    const int lr   = lane & 15;
    const int lq   = lane >> 4;

    const int wg   = blockIdx.x;
    const int lay  = wg >> 6;
    const int slot = wg & 63;
    const int j0   = slot * 16;

    int* fl0   = flags;
    int* flown = lay ? (flags + 64 * 32) : flags;

    const unsigned short* wih = lay ? wih1 : wih0;
    const unsigned short* whh = lay ? whh1 : whh0;
    const float* bih = lay ? bih1 : bih0;
    const float* bhh = lay ? bhh1 : bhh0;
    unsigned short* hb[2];
    if (lay == 0) { hb[0] = hb00; hb[1] = hb01; }
    else          { hb[0] = hb10; hb[1] = hb11; }

    // ---- stage w_hh rows {g*1024+j0 .. +16} into LDS, fragment-blob order ----
    for (int c = tid; c < 6144; c += 256) {
        int g   = c >> 11;
        int rem = c & 2047;
        int kt  = rem >> 6;
        int q   = (rem >> 4) & 3;
        int col = rem & 15;
        *(short8*)(blob + c * 8) =
            *(const short8*)((const short*)whh + (size_t)(g * 1024 + j0 + col) * 1024 + kt * 32 + q * 8);
    }

    // ---- per-thread gate constants + local f32 h init (threads 0..127: 4 cols each) ----
    float br_[4], bz_[4], bxn_[4], bhn_[4];
    if (tid < 128) {
        const int b = tid >> 2, c4 = (tid & 3) * 4;
#pragma unroll
        for (int j = 0; j < 4; ++j) {
            int gc = j0 + c4 + j;
            br_[j]  = bih[gc] + bhh[gc];
            bz_[j]  = bih[1024 + gc] + bhh[1024 + gc];
            bxn_[j] = bih[2048 + gc];
            bhn_[j] = bhh[2048 + gc];
        }
        float4 h0 = *(const float4*)&hid[(size_t)lay * NB * NH + (size_t)b * 1024 + j0 + c4];
        *(float4*)&hloc[b * 16 + c4] = h0;
    }
    __syncthreads();

    const int aoff = (mt * 16 + lr) * 1024 + lq * 8;   // element offset into [32][1024] slab
    const short* wiB = (const short*)wih + (size_t)(j0 + lr) * 1024 + lq * 8;

    for (int t = 0; t < NT; ++t) {
        if (lay == 1) {
            // y0b[t] must be fully published by layer 0
            if (wv == 0) {
                const int* p = fl0 + lane * 32;
                while (__hip_atomic_load(p, __ATOMIC_RELAXED, __HIP_MEMORY_SCOPE_AGENT) < t + 1)
                    __builtin_amdgcn_s_sleep(1);
            }
            asm volatile("" ::: "memory");
            __syncthreads();
        }

        f32x4 acc0 = {0.f,0.f,0.f,0.f};   // r (proj+rec)
        f32x4 acc1 = {0.f,0.f,0.f,0.f};   // z (proj+rec)
        f32x4 acc2 = {0.f,0.f,0.f,0.f};   // n proj only
        f32x4 acc3 = {0.f,0.f,0.f,0.f};   // n rec only

        // ---- input-projection phase (independent of h_t) ----
        if (lay == 0) {
            const short* Ap = (const short*)xt + (size_t)t * NB * 1024 + aoff;
#pragma unroll 8
            for (int kk = 0; kk < 16; ++kk) {
                const int kt = kh * 16 + kk;
                short8 a  = *(const short8*)(Ap + kt * 32);
                short8 b0 = *(const short8*)(wiB + kt * 32);
                short8 b1 = *(const short8*)(wiB + 1024 * 1024 + kt * 32);
                short8 b2 = *(const short8*)(wiB + 2 * 1024 * 1024 + kt * 32);
                acc0 = __builtin_amdgcn_mfma_f32_16x16x32_bf16(a, b0, acc0, 0, 0, 0);
                acc1 = __builtin_amdgcn_mfma_f32_16x16x32_bf16(a, b1, acc1, 0, 0, 0);
                acc2 = __builtin_amdgcn_mfma_f32_16x16x32_bf16(a, b2, acc2, 0, 0, 0);
            }
        } else {
            const u64* Ap = (const u64*)((const short*)y0b + (size_t)t * NB * 1024 + aoff);
#pragma unroll 8
            for (int kk = 0; kk < 16; ++kk) {
                const int kt = kh * 16 + kk;
                short8 a  = coh_load16(Ap + kt * 8);
                short8 b0 = *(const short8*)(wiB + kt * 32);
                short8 b1 = *(const short8*)(wiB + 1024 * 1024 + kt * 32);
                short8 b2 = *(const short8*)(wiB + 2 * 1024 * 1024 + kt * 32);
                acc0 = __builtin_amdgcn_mfma_f32_16x16x32_bf16(a, b0, acc0, 0, 0, 0);
                acc1 = __builtin_amdgcn_mfma_f32_16x16x32_bf16(a, b1, acc1, 0, 0, 0);
                acc2 = __builtin_amdgcn_mfma_f32_16x16x32_bf16(a, b2, acc2, 0, 0, 0);
            }
        }

        // ---- wait for peers' h_t (overlapped with proj above) ----
        if (wv == 0) {
            const int* p = flown + lane * 32;
            while (__hip_atomic_load(p, __ATOMIC_RELAXED, __HIP_MEMORY_SCOPE_AGENT) < t)
                __builtin_amdgcn_s_sleep(1);
        }
        asm volatile("" ::: "memory");
        __syncthreads();

        // ---- recurrent phase (coherent h reads) ----
        {
            const u64* Hb = (const u64*)((const short*)hb[t & 1] + aoff);
#pragma unroll 8
            for (int kk = 0; kk < 16; ++kk) {
                const int kt = kh * 16 + kk;
                short8 a  = coh_load16(Hb + kt * 8);
                short8 c0 = *(const short8*)(blob + kt * 512 + lane * 8);
                short8 c1 = *(const short8*)(blob + (32 + kt) * 512 + lane * 8);
                short8 c2 = *(const short8*)(blob + (64 + kt) * 512 + lane * 8);
                acc0 = __builtin_amdgcn_mfma_f32_16x16x32_bf16(a, c0, acc0, 0, 0, 0);
                acc1 = __builtin_amdgcn_mfma_f32_16x16x32_bf16(a, c1, acc1, 0, 0, 0);
                acc3 = __builtin_amdgcn_mfma_f32_16x16x32_bf16(a, c2, acc3, 0, 0, 0);
            }
        }

        *(f32x4*)(part + ((wv * 4 + 0) * 64 + lane) * 4) = acc0;
        *(f32x4*)(part + ((wv * 4 + 1) * 64 + lane) * 4) = acc1;
        *(f32x4*)(part + ((wv * 4 + 2) * 64 + lane) * 4) = acc2;
        *(f32x4*)(part + ((wv * 4 + 3) * 64 + lane) * 4) = acc3;
        __syncthreads();

        // reduce K-halves: hpf[g][b][c] = sum_kh part
        for (int eo = tid; eo < 2048; eo += 256) {
            int g2 = eo >> 9, b = (eo >> 4) & 31, c = eo & 15;
            int m = b >> 4, r = b & 3, l = ((b >> 2) & 3) * 16 + c;
            float v = part[(((m * 2 + 0) * 4 + g2) * 64 + l) * 4 + r]
                    + part[(((m * 2 + 1) * 4 + g2) * 64 + l) * 4 + r];
            hpf[eo] = v;
        }
        __syncthreads();

        // ---- gates: thread (tid<128) owns (b, 4 consecutive cols) ----
        if (tid < 128) {
            const int b = tid >> 2, c4 = (tid & 3) * 4;
            const int gc0 = j0 + c4;
            float hn[4];
            u64 hpack = 0;
#pragma unroll
            for (int j = 0; j < 4; ++j) {
                const int e = b * 16 + c4 + j;
                float pr  = hpf[e];
                float pz  = hpf[512 + e];
                float pxn = hpf[1024 + e];
                float phn = hpf[1536 + e];
                float r = 1.f / (1.f + __expf(-(pr + br_[j])));
                float z = 1.f / (1.f + __expf(-(pz + bz_[j])));
                float n = tanhf(pxn + bxn_[j] + r * (phn + bhn_[j]));
                float hprev = hloc[e];
                float h = (1.f - z) * n + z * hprev;
                hloc[e] = h;
                hn[j] = h;
                hpack |= (u64)f2bf(h) << (16 * j);
            }
            coh_store8((u64*)((unsigned short*)hb[(t + 1) & 1] + (size_t)b * 1024 + gc0), hpack);
            if (lay == 0) {
                coh_store8((u64*)(y0b + ((size_t)t * NB + b) * 1024 + gc0), hpack);
            } else {
                float4 o4; o4.x = hn[0]; o4.y = hn[1]; o4.z = hn[2]; o4.w = hn[3];
                *(float4*)&out[((size_t)b * NT + t) * 1024 + gc0] = o4;
            }
            if (t == NT - 1) {
                float4 o4; o4.x = hn[0]; o4.y = hn[1]; o4.z = hn[2]; o4.w = hn[3];
                *(float4*)&out[(size_t)NB * NT * 1024 + (size_t)lay * NB * NH + (size_t)b * 1024 + gc0] = o4;
            }
        }

        // drain own stores, then block-wide rendezvous, then publish
        asm volatile("s_waitcnt vmcnt(0)" ::: "memory");
        __syncthreads();
        if (tid == 0)
            __hip_atomic_store(flown + slot * 32, t + 1, __ATOMIC_RELAXED, __HIP_MEMORY_SCOPE_AGENT);
    }
}

extern "C" void kernel_launch(void* const* d_in, const int* in_sizes, int n_in,
                              void* d_out, int out_size, void* d_ws, size_t ws_size,
                              hipStream_t stream) {
    (void)in_sizes; (void)n_in; (void)out_size; (void)ws_size;

    const float* x     = (const float*)d_in[0];
    const float* hid   = (const float*)d_in[1];
    const float* w_ih0 = (const float*)d_in[2];
    const float* w_hh0 = (const float*)d_in[3];
    const float* b_ih0 = (const float*)d_in[4];
    const float* b_hh0 = (const float*)d_in[5];
    const float* w_ih1 = (const float*)d_in[6];
    const float* w_hh1 = (const float*)d_in[7];
    const float* b_ih1 = (const float*)d_in[8];
    const float* b_hh1 = (const float*)d_in[9];
    float* out = (float*)d_out;

    char* ws = (char*)d_ws;
    size_t off = 0;
    auto alloc = [&](size_t bytes) -> void* {
        void* p = ws + off;
        off += (bytes + 255) & ~(size_t)255;
        return p;
    };

    unsigned short* xtb   = (unsigned short*)alloc((size_t)NT * NB * 1024 * 2);
    unsigned short* y0b   = (unsigned short*)alloc((size_t)NT * NB * 1024 * 2);
    unsigned short* wih0b = (unsigned short*)alloc((size_t)G3 * 1024 * 2);
    unsigned short* whh0b = (unsigned short*)alloc((size_t)G3 * 1024 * 2);
    unsigned short* wih1b = (unsigned short*)alloc((size_t)G3 * 1024 * 2);
    unsigned short* whh1b = (unsigned short*)alloc((size_t)G3 * 1024 * 2);
    unsigned short* hb0[2]; unsigned short* hb1[2];
    for (int i = 0; i < 2; i++) hb0[i] = (unsigned short*)alloc(NB * NH * 2);
    for (int i = 0; i < 2; i++) hb1[i] = (unsigned short*)alloc(NB * NH * 2);
    int* flags = (int*)alloc(2 * 64 * 32 * sizeof(int));   // 16 KB, 128B-spaced slots

    // --- conversions / init ---
    txp_x<<<2048, 256, 0, stream>>>((const float4*)x, (us4*)xtb);
    cvt_bf16_v4<<<512, 256, 0, stream>>>((const float4*)w_ih0, (us4*)wih0b, G3 * 1024 / 4);
    cvt_bf16_v4<<<512, 256, 0, stream>>>((const float4*)w_hh0, (us4*)whh0b, G3 * 1024 / 4);
    cvt_bf16_v4<<<512, 256, 0, stream>>>((const float4*)w_ih1, (us4*)wih1b, G3 * 1024 / 4);
    cvt_bf16_v4<<<512, 256, 0, stream>>>((const float4*)w_hh1, (us4*)whh1b, G3 * 1024 / 4);
    init_h<<<NB * NH / 256, 256, 0, stream>>>(hid, hb0[0], hb1[0]);
    hipMemsetAsync(flags, 0, 2 * 64 * 32 * sizeof(int), stream);

    // --- persistent recurrence (both layers, wavefront-pipelined) ---
    (void)hipFuncSetAttribute((const void*)gru_persistent,
                              hipFuncAttributeMaxDynamicSharedMemorySize, PK_LDS);
    gru_persistent<<<NWG, 256, PK_LDS, stream>>>(
        xtb, y0b, wih0b, whh0b, wih1b, whh1b,
        b_ih0, b_hh0, b_ih1, b_hh1, hid,
        hb0[0], hb0[1], hb1[0], hb1[1],
        out, flags);
}

// Round 5
// 7768.885 us; speedup vs baseline: 1.0783x; 1.0783x over previous
//
#include <hip/hip_runtime.h>
#include <hip/hip_bf16.h>

#define NB 32
#define NT 512
#define NH 1024
#define G3 3072
#define NWG 128
#define LDS_BLOB 98304
#define LDS_PART 16384
#define LDS_HPF  8192
#define LDS_HLOC 2048
#define PK_LDS (LDS_BLOB + LDS_PART + LDS_HPF + LDS_HLOC)

typedef __attribute__((ext_vector_type(8))) short short8;
typedef __attribute__((ext_vector_type(4))) float f32x4;
typedef __attribute__((ext_vector_type(4))) unsigned short us4;
typedef unsigned long long u64;

static __device__ __forceinline__ unsigned short f2bf(float f) {
    union { float f; unsigned u; } v; v.f = f;
    if ((v.u & 0x7fffffffu) > 0x7f800000u) return (unsigned short)((v.u >> 16) | 0x0040u);
    unsigned u = v.u + 0x7fffu + ((v.u >> 16) & 1u);
    return (unsigned short)(u >> 16);
}

// coherent (LLC point) 16B load as two relaxed agent-scope u64 atomics
static __device__ __forceinline__ short8 coh_load16(const u64* p) {
    u64 lo = __hip_atomic_load(p,     __ATOMIC_RELAXED, __HIP_MEMORY_SCOPE_AGENT);
    u64 hi = __hip_atomic_load(p + 1, __ATOMIC_RELAXED, __HIP_MEMORY_SCOPE_AGENT);
    union { u64 u[2]; short8 s; } r;
    r.u[0] = lo; r.u[1] = hi;
    return r.s;
}
static __device__ __forceinline__ void coh_store8(u64* p, u64 v) {
    __hip_atomic_store(p, v, __ATOMIC_RELAXED, __HIP_MEMORY_SCOPE_AGENT);
}

// ---------------- f32 -> bf16 conversion (vectorized) ----------------
__global__ __launch_bounds__(256) void cvt_bf16_v4(const float4* __restrict__ src,
                                                   us4* __restrict__ dst, int n4) {
    for (int i = blockIdx.x * 256 + threadIdx.x; i < n4; i += gridDim.x * 256) {
        float4 v = src[i];
        us4 o;
        o.x = f2bf(v.x); o.y = f2bf(v.y); o.z = f2bf(v.z); o.w = f2bf(v.w);
        dst[i] = o;
    }
}

// ---------------- x [B][T][D] f32 -> xt [T][B][D] bf16 ----------------
__global__ __launch_bounds__(256) void txp_x(const float4* __restrict__ x, us4* __restrict__ xt) {
    const int total = NT * NB * 256;   // in float4 units
    for (int i = blockIdx.x * 256 + threadIdx.x; i < total; i += gridDim.x * 256) {
        int b = i / (NT * 256);
        int rem = i - b * (NT * 256);
        int t = rem >> 8;
        int d4 = rem & 255;
        float4 v = x[i];
        us4 o;
        o.x = f2bf(v.x); o.y = f2bf(v.y); o.z = f2bf(v.z); o.w = f2bf(v.w);
        xt[((size_t)t * NB + b) * 256 + d4] = o;
    }
}

// ---------------- init hidden bf16 shadows ----------------
__global__ __launch_bounds__(256) void init_h(const float* __restrict__ hid,
                                              unsigned short* __restrict__ h0b,
                                              unsigned short* __restrict__ h1b) {
    int i = blockIdx.x * 256 + threadIdx.x;   // grid covers exactly NB*NH
    h0b[i] = f2bf(hid[i]);
    h1b[i] = f2bf(hid[NB * NH + i]);
}

// ---------------- persistent 2-layer GRU, packed-flag per-wave sync ----------------
// flags layout: [layer][half][64] ints. half h covers batches h*16..h*16+15.
// flag[lay][h][slot] == t+1  <=>  WG slot of layer lay has published
// h_{t+1}[batches of half h][cols slot*16..+16] (and y0[t] for lay==0).
__global__ __launch_bounds__(256, 1) void gru_persistent(
    const unsigned short* __restrict__ xt,      // [T][B][1024] bf16
    unsigned short* __restrict__ y0b,           // [T][B][1024] bf16 (coherent)
    const unsigned short* __restrict__ wih0, const unsigned short* __restrict__ whh0,
    const unsigned short* __restrict__ wih1, const unsigned short* __restrict__ whh1,
    const float* __restrict__ bih0, const float* __restrict__ bhh0,
    const float* __restrict__ bih1, const float* __restrict__ bhh1,
    const float* __restrict__ hid,              // [2][B][1024] f32
    unsigned short* __restrict__ hb00, unsigned short* __restrict__ hb01,
    unsigned short* __restrict__ hb10, unsigned short* __restrict__ hb11,
    float* __restrict__ out,                    // y1 [B][T][1024] f32, then h [2][B][1024]
    int* __restrict__ flags)
{
    extern __shared__ char lds[];
    short* blob = (short*)lds;                               // w_hh fragment blobs
    float* part = (float*)(lds + LDS_BLOB);                  // per-wave partials
    float* hpf  = (float*)(lds + LDS_BLOB + LDS_PART);       // reduced pre-acts [4][32][16]
    float* hloc = (float*)(lds + LDS_BLOB + LDS_PART + LDS_HPF); // f32 h_prev [32][16]

    const int tid  = threadIdx.x;
    const int lane = tid & 63;
    const int wv   = tid >> 6;      // 0..3
    const int kh   = wv & 1;        // K-half
    const int mt   = wv >> 1;       // M-tile (batch 0-15 / 16-31)
    const int lr   = lane & 15;
    const int lq   = lane >> 4;

    const int wg   = blockIdx.x;
    const int lay  = wg >> 6;
    const int slot = wg & 63;
    const int j0   = slot * 16;

    // per-wave poll pointers (64 packed ints per half)
    const int* poll_own = flags + lay * 128 + mt * 64 + lane;
    const int* poll_y0  = flags + mt * 64 + lane;              // layer-0 flags
    int* pub = flags + lay * 128 + (tid >> 6) * 64 + slot;     // valid for wv 0/1

    const unsigned short* wih = lay ? wih1 : wih0;
    const unsigned short* whh = lay ? whh1 : whh0;
    const float* bih = lay ? bih1 : bih0;
    const float* bhh = lay ? bhh1 : bhh0;
    unsigned short* hb[2];
    if (lay == 0) { hb[0] = hb00; hb[1] = hb01; }
    else          { hb[0] = hb10; hb[1] = hb11; }

    // ---- stage w_hh rows {g*1024+j0 .. +16} into LDS, fragment-blob order ----
    for (int c = tid; c < 6144; c += 256) {
        int g   = c >> 11;
        int rem = c & 2047;
        int kt  = rem >> 6;
        int q   = (rem >> 4) & 3;
        int col = rem & 15;
        *(short8*)(blob + c * 8) =
            *(const short8*)((const short*)whh + (size_t)(g * 1024 + j0 + col) * 1024 + kt * 32 + q * 8);
    }

    // ---- per-thread gate constants + local f32 h init (threads 0..127: 4 cols each) ----
    float br_[4], bz_[4], bxn_[4], bhn_[4];
    if (tid < 128) {
        const int b = tid >> 2, c4 = (tid & 3) * 4;
#pragma unroll
        for (int j = 0; j < 4; ++j) {
            int gc = j0 + c4 + j;
            br_[j]  = bih[gc] + bhh[gc];
            bz_[j]  = bih[1024 + gc] + bhh[1024 + gc];
            bxn_[j] = bih[2048 + gc];
            bhn_[j] = bhh[2048 + gc];
        }
        float4 h0 = *(const float4*)&hid[(size_t)lay * NB * NH + (size_t)b * 1024 + j0 + c4];
        *(float4*)&hloc[b * 16 + c4] = h0;
    }
    __syncthreads();

    const int aoff = (mt * 16 + lr) * 1024 + lq * 8;   // element offset into [32][1024] slab
    const short* wiB = (const short*)wih + (size_t)(j0 + lr) * 1024 + lq * 8;

    for (int t = 0; t < NT; ++t) {
        f32x4 acc0 = {0.f,0.f,0.f,0.f};   // r (proj+rec)
        f32x4 acc1 = {0.f,0.f,0.f,0.f};   // z (proj+rec)
        f32x4 acc2 = {0.f,0.f,0.f,0.f};   // n proj only
        f32x4 acc3 = {0.f,0.f,0.f,0.f};   // n rec only

        // ---- input-projection phase (independent of h_t) ----
        if (lay == 0) {
            const short* Ap = (const short*)xt + (size_t)t * NB * 1024 + aoff;
#pragma unroll 8
            for (int kk = 0; kk < 16; ++kk) {
                const int kt = kh * 16 + kk;
                short8 a  = *(const short8*)(Ap + kt * 32);
                short8 b0 = *(const short8*)(wiB + kt * 32);
                short8 b1 = *(const short8*)(wiB + 1024 * 1024 + kt * 32);
                short8 b2 = *(const short8*)(wiB + 2 * 1024 * 1024 + kt * 32);
                acc0 = __builtin_amdgcn_mfma_f32_16x16x32_bf16(a, b0, acc0, 0, 0, 0);
                acc1 = __builtin_amdgcn_mfma_f32_16x16x32_bf16(a, b1, acc1, 0, 0, 0);
                acc2 = __builtin_amdgcn_mfma_f32_16x16x32_bf16(a, b2, acc2, 0, 0, 0);
            }
        } else {
            // wait for layer 0 to publish y0[t] for this wave's batch half
            while (__hip_atomic_load(poll_y0, __ATOMIC_RELAXED, __HIP_MEMORY_SCOPE_AGENT) < t + 1)
                __builtin_amdgcn_s_sleep(1);
            asm volatile("" ::: "memory");
            const u64* Ap = (const u64*)((const short*)y0b + (size_t)t * NB * 1024 + aoff);
#pragma unroll 8
            for (int kk = 0; kk < 16; ++kk) {
                const int kt = kh * 16 + kk;
                short8 a  = coh_load16(Ap + kt * 8);
                short8 b0 = *(const short8*)(wiB + kt * 32);
                short8 b1 = *(const short8*)(wiB + 1024 * 1024 + kt * 32);
                short8 b2 = *(const short8*)(wiB + 2 * 1024 * 1024 + kt * 32);
                acc0 = __builtin_amdgcn_mfma_f32_16x16x32_bf16(a, b0, acc0, 0, 0, 0);
                acc1 = __builtin_amdgcn_mfma_f32_16x16x32_bf16(a, b1, acc1, 0, 0, 0);
                acc2 = __builtin_amdgcn_mfma_f32_16x16x32_bf16(a, b2, acc2, 0, 0, 0);
            }
        }

        // ---- wait for peers' h_t for this wave's batch half (overlapped with proj) ----
        while (__hip_atomic_load(poll_own, __ATOMIC_RELAXED, __HIP_MEMORY_SCOPE_AGENT) < t)
            __builtin_amdgcn_s_sleep(1);
        asm volatile("" ::: "memory");

        // ---- recurrent phase (coherent h reads) ----
        {
            const u64* Hb = (const u64*)((const short*)hb[t & 1] + aoff);
#pragma unroll 8
            for (int kk = 0; kk < 16; ++kk) {
                const int kt = kh * 16 + kk;
                short8 a  = coh_load16(Hb + kt * 8);
                short8 c0 = *(const short8*)(blob + kt * 512 + lane * 8);
                short8 c1 = *(const short8*)(blob + (32 + kt) * 512 + lane * 8);
                short8 c2 = *(const short8*)(blob + (64 + kt) * 512 + lane * 8);
                acc0 = __builtin_amdgcn_mfma_f32_16x16x32_bf16(a, c0, acc0, 0, 0, 0);
                acc1 = __builtin_amdgcn_mfma_f32_16x16x32_bf16(a, c1, acc1, 0, 0, 0);
                acc3 = __builtin_amdgcn_mfma_f32_16x16x32_bf16(a, c2, acc3, 0, 0, 0);
            }
        }

        *(f32x4*)(part + ((wv * 4 + 0) * 64 + lane) * 4) = acc0;
        *(f32x4*)(part + ((wv * 4 + 1) * 64 + lane) * 4) = acc1;
        *(f32x4*)(part + ((wv * 4 + 2) * 64 + lane) * 4) = acc2;
        *(f32x4*)(part + ((wv * 4 + 3) * 64 + lane) * 4) = acc3;
        __syncthreads();

        // reduce K-halves: hpf[g][b][c] = sum_kh part
        for (int eo = tid; eo < 2048; eo += 256) {
            int g2 = eo >> 9, b = (eo >> 4) & 31, c = eo & 15;
            int m = b >> 4, r = b & 3, l = ((b >> 2) & 3) * 16 + c;
            float v = part[(((m * 2 + 0) * 4 + g2) * 64 + l) * 4 + r]
                    + part[(((m * 2 + 1) * 4 + g2) * 64 + l) * 4 + r];
            hpf[eo] = v;
        }
        __syncthreads();

        // ---- gates: waves 0/1, thread owns (b, 4 consecutive cols) ----
        if (tid < 128) {
            const int b = tid >> 2, c4 = (tid & 3) * 4;
            const int gc0 = j0 + c4;
            float hn[4];
            u64 hpack = 0;
#pragma unroll
            for (int j = 0; j < 4; ++j) {
                const int e = b * 16 + c4 + j;
                float pr  = hpf[e];
                float pz  = hpf[512 + e];
                float pxn = hpf[1024 + e];
                float phn = hpf[1536 + e];
                float r = 1.f / (1.f + __expf(-(pr + br_[j])));
                float z = 1.f / (1.f + __expf(-(pz + bz_[j])));
                float na = pxn + bxn_[j] + r * (phn + bhn_[j]);
                float e2 = __expf(-2.f * na);
                float n = (1.f - e2) / (1.f + e2);      // tanh(na)
                float hprev = hloc[e];
                float h = (1.f - z) * n + z * hprev;
                hloc[e] = h;
                hn[j] = h;
                hpack |= (u64)f2bf(h) << (16 * j);
            }
            coh_store8((u64*)((unsigned short*)hb[(t + 1) & 1] + (size_t)b * 1024 + gc0), hpack);
            if (lay == 0)
                coh_store8((u64*)(y0b + ((size_t)t * NB + b) * 1024 + gc0), hpack);

            // per-wave drain of the coherent stores, then publish this half's flag
            asm volatile("s_waitcnt vmcnt(0)" ::: "memory");
            if ((tid & 63) == 0)
                __hip_atomic_store(pub, t + 1, __ATOMIC_RELAXED, __HIP_MEMORY_SCOPE_AGENT);

            // non-consumed outputs go out AFTER the publish (off the critical path)
            if (lay == 1) {
                float4 o4; o4.x = hn[0]; o4.y = hn[1]; o4.z = hn[2]; o4.w = hn[3];
                *(float4*)&out[((size_t)b * NT + t) * 1024 + gc0] = o4;
            }
            if (t == NT - 1) {
                float4 o4; o4.x = hn[0]; o4.y = hn[1]; o4.z = hn[2]; o4.w = hn[3];
                *(float4*)&out[(size_t)NB * NT * 1024 + (size_t)lay * NB * NH + (size_t)b * 1024 + gc0] = o4;
            }
        }
        // no block-wide barrier: next step's __syncthreads (after part store)
        // provides the intra-WG rendezvous; cross-WG ordering is via flags.
    }
}

extern "C" void kernel_launch(void* const* d_in, const int* in_sizes, int n_in,
                              void* d_out, int out_size, void* d_ws, size_t ws_size,
                              hipStream_t stream) {
    (void)in_sizes; (void)n_in; (void)out_size; (void)ws_size;

    const float* x     = (const float*)d_in[0];
    const float* hid   = (const float*)d_in[1];
    const float* w_ih0 = (const float*)d_in[2];
    const float* w_hh0 = (const float*)d_in[3];
    const float* b_ih0 = (const float*)d_in[4];
    const float* b_hh0 = (const float*)d_in[5];
    const float* w_ih1 = (const float*)d_in[6];
    const float* w_hh1 = (const float*)d_in[7];
    const float* b_ih1 = (const float*)d_in[8];
    const float* b_hh1 = (const float*)d_in[9];
    float* out = (float*)d_out;

    char* ws = (char*)d_ws;
    size_t off = 0;
    auto alloc = [&](size_t bytes) -> void* {
        void* p = ws + off;
        off += (bytes + 255) & ~(size_t)255;
        return p;
    };

    unsigned short* xtb   = (unsigned short*)alloc((size_t)NT * NB * 1024 * 2);
    unsigned short* y0b   = (unsigned short*)alloc((size_t)NT * NB * 1024 * 2);
    unsigned short* wih0b = (unsigned short*)alloc((size_t)G3 * 1024 * 2);
    unsigned short* whh0b = (unsigned short*)alloc((size_t)G3 * 1024 * 2);
    unsigned short* wih1b = (unsigned short*)alloc((size_t)G3 * 1024 * 2);
    unsigned short* whh1b = (unsigned short*)alloc((size_t)G3 * 1024 * 2);
    unsigned short* hb0[2]; unsigned short* hb1[2];
    for (int i = 0; i < 2; i++) hb0[i] = (unsigned short*)alloc(NB * NH * 2);
    for (int i = 0; i < 2; i++) hb1[i] = (unsigned short*)alloc(NB * NH * 2);
    int* flags = (int*)alloc(2 * 2 * 64 * sizeof(int));   // packed: [layer][half][64]

    // --- conversions / init ---
    txp_x<<<2048, 256, 0, stream>>>((const float4*)x, (us4*)xtb);
    cvt_bf16_v4<<<512, 256, 0, stream>>>((const float4*)w_ih0, (us4*)wih0b, G3 * 1024 / 4);
    cvt_bf16_v4<<<512, 256, 0, stream>>>((const float4*)w_hh0, (us4*)whh0b, G3 * 1024 / 4);
    cvt_bf16_v4<<<512, 256, 0, stream>>>((const float4*)w_ih1, (us4*)wih1b, G3 * 1024 / 4);
    cvt_bf16_v4<<<512, 256, 0, stream>>>((const float4*)w_hh1, (us4*)whh1b, G3 * 1024 / 4);
    init_h<<<NB * NH / 256, 256, 0, stream>>>(hid, hb0[0], hb1[0]);
    hipMemsetAsync(flags, 0, 2 * 2 * 64 * sizeof(int), stream);

    // --- persistent recurrence (both layers, wavefront-pipelined) ---
    (void)hipFuncSetAttribute((const void*)gru_persistent,
                              hipFuncAttributeMaxDynamicSharedMemorySize, PK_LDS);
    gru_persistent<<<NWG, 256, PK_LDS, stream>>>(
        xtb, y0b, wih0b, whh0b, wih1b, whh1b,
        b_ih0, b_hh0, b_ih1, b_hh1, hid,
        hb0[0], hb0[1], hb1[0], hb1[1],
        out, flags);
}

// Round 6
// 7019.715 us; speedup vs baseline: 1.1934x; 1.1067x over previous
//
#include <hip/hip_runtime.h>
#include <hip/hip_bf16.h>

#define NB 32
#define NT 512
#define NH 1024
#define G3 3072
#define NWG 128
#define LDS_BLOB 98304
#define LDS_PART 16384
#define LDS_HPF  8192
#define LDS_HLOC 2048
#define PK_LDS (LDS_BLOB + LDS_PART + LDS_HPF + LDS_HLOC)

typedef __attribute__((ext_vector_type(8))) short short8;
typedef __attribute__((ext_vector_type(4))) float f32x4;
typedef __attribute__((ext_vector_type(4))) unsigned short us4;
typedef unsigned long long u64;

static __device__ __forceinline__ unsigned short f2bf(float f) {
    union { float f; unsigned u; } v; v.f = f;
    if ((v.u & 0x7fffffffu) > 0x7f800000u) return (unsigned short)((v.u >> 16) | 0x0040u);
    unsigned u = v.u + 0x7fffu + ((v.u >> 16) & 1u);
    return (unsigned short)(u >> 16);
}

static __device__ __forceinline__ void coh_store8(u64* p, u64 v) {
    __hip_atomic_store(p, v, __ATOMIC_RELAXED, __HIP_MEMORY_SCOPE_AGENT);
}

// 16 coherent (L1/L2-bypassing) 16B loads at byte offsets 0,64,...,960 from
// base, issued back-to-back with a single vmcnt(0) drain. One LLC round trip
// instead of 16 serialized ones.
static __device__ __forceinline__ void coh_load_1KB(const char* base, short8 o[16]) {
    asm volatile(
        "global_load_dwordx4 %0,  %16, off sc0 sc1\n\t"
        "global_load_dwordx4 %1,  %16, off offset:64 sc0 sc1\n\t"
        "global_load_dwordx4 %2,  %16, off offset:128 sc0 sc1\n\t"
        "global_load_dwordx4 %3,  %16, off offset:192 sc0 sc1\n\t"
        "global_load_dwordx4 %4,  %16, off offset:256 sc0 sc1\n\t"
        "global_load_dwordx4 %5,  %16, off offset:320 sc0 sc1\n\t"
        "global_load_dwordx4 %6,  %16, off offset:384 sc0 sc1\n\t"
        "global_load_dwordx4 %7,  %16, off offset:448 sc0 sc1\n\t"
        "global_load_dwordx4 %8,  %16, off offset:512 sc0 sc1\n\t"
        "global_load_dwordx4 %9,  %16, off offset:576 sc0 sc1\n\t"
        "global_load_dwordx4 %10, %16, off offset:640 sc0 sc1\n\t"
        "global_load_dwordx4 %11, %16, off offset:704 sc0 sc1\n\t"
        "global_load_dwordx4 %12, %16, off offset:768 sc0 sc1\n\t"
        "global_load_dwordx4 %13, %16, off offset:832 sc0 sc1\n\t"
        "global_load_dwordx4 %14, %16, off offset:896 sc0 sc1\n\t"
        "global_load_dwordx4 %15, %16, off offset:960 sc0 sc1\n\t"
        "s_waitcnt vmcnt(0)"
        : "=&v"(o[0]), "=&v"(o[1]), "=&v"(o[2]), "=&v"(o[3]),
          "=&v"(o[4]), "=&v"(o[5]), "=&v"(o[6]), "=&v"(o[7]),
          "=&v"(o[8]), "=&v"(o[9]), "=&v"(o[10]), "=&v"(o[11]),
          "=&v"(o[12]), "=&v"(o[13]), "=&v"(o[14]), "=&v"(o[15])
        : "v"(base)
        : "memory");
    __builtin_amdgcn_sched_barrier(0);
}

// ---------------- f32 -> bf16 conversion (vectorized) ----------------
__global__ __launch_bounds__(256) void cvt_bf16_v4(const float4* __restrict__ src,
                                                   us4* __restrict__ dst, int n4) {
    for (int i = blockIdx.x * 256 + threadIdx.x; i < n4; i += gridDim.x * 256) {
        float4 v = src[i];
        us4 o;
        o.x = f2bf(v.x); o.y = f2bf(v.y); o.z = f2bf(v.z); o.w = f2bf(v.w);
        dst[i] = o;
    }
}

// ---------------- x [B][T][D] f32 -> xt [T][B][D] bf16 ----------------
__global__ __launch_bounds__(256) void txp_x(const float4* __restrict__ x, us4* __restrict__ xt) {
    const int total = NT * NB * 256;   // in float4 units
    for (int i = blockIdx.x * 256 + threadIdx.x; i < total; i += gridDim.x * 256) {
        int b = i / (NT * 256);
        int rem = i - b * (NT * 256);
        int t = rem >> 8;
        int d4 = rem & 255;
        float4 v = x[i];
        us4 o;
        o.x = f2bf(v.x); o.y = f2bf(v.y); o.z = f2bf(v.z); o.w = f2bf(v.w);
        xt[((size_t)t * NB + b) * 256 + d4] = o;
    }
}

// ---------------- init hidden bf16 shadows ----------------
__global__ __launch_bounds__(256) void init_h(const float* __restrict__ hid,
                                              unsigned short* __restrict__ h0b,
                                              unsigned short* __restrict__ h1b) {
    int i = blockIdx.x * 256 + threadIdx.x;   // grid covers exactly NB*NH
    h0b[i] = f2bf(hid[i]);
    h1b[i] = f2bf(hid[NB * NH + i]);
}

// ---------------- persistent 2-layer GRU, packed-flag per-wave sync ----------------
// flags layout: [layer][half][64] ints. half h covers batches h*16..h*16+15.
__global__ __launch_bounds__(256, 1) void gru_persistent(
    const unsigned short* __restrict__ xt,      // [T][B][1024] bf16
    unsigned short* __restrict__ y0b,           // [T][B][1024] bf16 (coherent)
    const unsigned short* __restrict__ wih0, const unsigned short* __restrict__ whh0,
    const unsigned short* __restrict__ wih1, const unsigned short* __restrict__ whh1,
    const float* __restrict__ bih0, const float* __restrict__ bhh0,
    const float* __restrict__ bih1, const float* __restrict__ bhh1,
    const float* __restrict__ hid,              // [2][B][1024] f32
    unsigned short* __restrict__ hb00, unsigned short* __restrict__ hb01,
    unsigned short* __restrict__ hb10, unsigned short* __restrict__ hb11,
    float* __restrict__ out,                    // y1 [B][T][1024] f32, then h [2][B][1024]
    int* __restrict__ flags)
{
    extern __shared__ char lds[];
    short* blob = (short*)lds;                               // w_hh fragment blobs
    float* part = (float*)(lds + LDS_BLOB);                  // per-wave partials
    float* hpf  = (float*)(lds + LDS_BLOB + LDS_PART);       // reduced pre-acts [4][32][16]
    float* hloc = (float*)(lds + LDS_BLOB + LDS_PART + LDS_HPF); // f32 h_prev [32][16]

    const int tid  = threadIdx.x;
    const int lane = tid & 63;
    const int wv   = tid >> 6;      // 0..3
    const int kh   = wv & 1;        // K-half
    const int mt   = wv >> 1;       // M-tile (batch 0-15 / 16-31)
    const int lr   = lane & 15;
    const int lq   = lane >> 4;

    const int wg   = blockIdx.x;
    const int lay  = wg >> 6;
    const int slot = wg & 63;
    const int j0   = slot * 16;

    // per-wave poll pointers (64 packed ints per half)
    const int* poll_own = flags + lay * 128 + mt * 64 + lane;
    const int* poll_y0  = flags + mt * 64 + lane;              // layer-0 flags
    int* pub = flags + lay * 128 + (tid >> 6) * 64 + slot;     // valid for wv 0/1

    const unsigned short* wih = lay ? wih1 : wih0;
    const unsigned short* whh = lay ? whh1 : whh0;
    const float* bih = lay ? bih1 : bih0;
    const float* bhh = lay ? bhh1 : bhh0;
    unsigned short* hb[2];
    if (lay == 0) { hb[0] = hb00; hb[1] = hb01; }
    else          { hb[0] = hb10; hb[1] = hb11; }

    // ---- stage w_hh rows {g*1024+j0 .. +16} into LDS, fragment-blob order ----
    for (int c = tid; c < 6144; c += 256) {
        int g   = c >> 11;
        int rem = c & 2047;
        int kt  = rem >> 6;
        int q   = (rem >> 4) & 3;
        int col = rem & 15;
        *(short8*)(blob + c * 8) =
            *(const short8*)((const short*)whh + (size_t)(g * 1024 + j0 + col) * 1024 + kt * 32 + q * 8);
    }

    // ---- per-thread gate constants + local f32 h init (threads 0..127: 4 cols each) ----
    float br_[4], bz_[4], bxn_[4], bhn_[4];
    if (tid < 128) {
        const int b = tid >> 2, c4 = (tid & 3) * 4;
#pragma unroll
        for (int j = 0; j < 4; ++j) {
            int gc = j0 + c4 + j;
            br_[j]  = bih[gc] + bhh[gc];
            bz_[j]  = bih[1024 + gc] + bhh[1024 + gc];
            bxn_[j] = bih[2048 + gc];
            bhn_[j] = bhh[2048 + gc];
        }
        float4 h0 = *(const float4*)&hid[(size_t)lay * NB * NH + (size_t)b * 1024 + j0 + c4];
        *(float4*)&hloc[b * 16 + c4] = h0;
    }
    __syncthreads();

    const int aoff = (mt * 16 + lr) * 1024 + lq * 8;   // element offset into [32][1024] slab
    const size_t aoff_b = (size_t)aoff * 2 + (size_t)kh * 1024;  // byte offset incl. K-half
    const short* wiB = (const short*)wih + (size_t)(j0 + lr) * 1024 + lq * 8;

    for (int t = 0; t < NT; ++t) {
        f32x4 acc0 = {0.f,0.f,0.f,0.f};   // r (proj+rec)
        f32x4 acc1 = {0.f,0.f,0.f,0.f};   // z (proj+rec)
        f32x4 acc2 = {0.f,0.f,0.f,0.f};   // n proj only
        f32x4 acc3 = {0.f,0.f,0.f,0.f};   // n rec only

        // ---- input-projection phase (independent of h_t) ----
        if (lay == 0) {
            const short* Ap = (const short*)xt + (size_t)t * NB * 1024 + aoff;
#pragma unroll 8
            for (int kk = 0; kk < 16; ++kk) {
                const int kt = kh * 16 + kk;
                short8 a  = *(const short8*)(Ap + kt * 32);
                short8 b0 = *(const short8*)(wiB + kt * 32);
                short8 b1 = *(const short8*)(wiB + 1024 * 1024 + kt * 32);
                short8 b2 = *(const short8*)(wiB + 2 * 1024 * 1024 + kt * 32);
                acc0 = __builtin_amdgcn_mfma_f32_16x16x32_bf16(a, b0, acc0, 0, 0, 0);
                acc1 = __builtin_amdgcn_mfma_f32_16x16x32_bf16(a, b1, acc1, 0, 0, 0);
                acc2 = __builtin_amdgcn_mfma_f32_16x16x32_bf16(a, b2, acc2, 0, 0, 0);
            }
        } else {
            // wait for layer 0 to publish y0[t] for this wave's batch half
            while (__hip_atomic_load(poll_y0, __ATOMIC_RELAXED, __HIP_MEMORY_SCOPE_AGENT) < t + 1)
                __builtin_amdgcn_s_sleep(1);
            asm volatile("" ::: "memory");
            short8 ya[16];
            coh_load_1KB((const char*)y0b + (size_t)t * NB * 1024 * 2 + aoff_b, ya);
#pragma unroll
            for (int kk = 0; kk < 16; ++kk) {
                const int kt = kh * 16 + kk;
                short8 b0 = *(const short8*)(wiB + kt * 32);
                short8 b1 = *(const short8*)(wiB + 1024 * 1024 + kt * 32);
                short8 b2 = *(const short8*)(wiB + 2 * 1024 * 1024 + kt * 32);
                acc0 = __builtin_amdgcn_mfma_f32_16x16x32_bf16(ya[kk], b0, acc0, 0, 0, 0);
                acc1 = __builtin_amdgcn_mfma_f32_16x16x32_bf16(ya[kk], b1, acc1, 0, 0, 0);
                acc2 = __builtin_amdgcn_mfma_f32_16x16x32_bf16(ya[kk], b2, acc2, 0, 0, 0);
            }
        }

        // ---- wait for peers' h_t for this wave's batch half (overlapped with proj) ----
        while (__hip_atomic_load(poll_own, __ATOMIC_RELAXED, __HIP_MEMORY_SCOPE_AGENT) < t)
            __builtin_amdgcn_s_sleep(1);
        asm volatile("" ::: "memory");

        // ---- recurrent phase: batched coherent h loads, then MFMAs ----
        {
            short8 ha[16];
            coh_load_1KB((const char*)hb[t & 1] + aoff_b, ha);
#pragma unroll
            for (int kk = 0; kk < 16; ++kk) {
                const int kt = kh * 16 + kk;
                short8 c0 = *(const short8*)(blob + kt * 512 + lane * 8);
                short8 c1 = *(const short8*)(blob + (32 + kt) * 512 + lane * 8);
                short8 c2 = *(const short8*)(blob + (64 + kt) * 512 + lane * 8);
                acc0 = __builtin_amdgcn_mfma_f32_16x16x32_bf16(ha[kk], c0, acc0, 0, 0, 0);
                acc1 = __builtin_amdgcn_mfma_f32_16x16x32_bf16(ha[kk], c1, acc1, 0, 0, 0);
                acc3 = __builtin_amdgcn_mfma_f32_16x16x32_bf16(ha[kk], c2, acc3, 0, 0, 0);
            }
        }

        *(f32x4*)(part + ((wv * 4 + 0) * 64 + lane) * 4) = acc0;
        *(f32x4*)(part + ((wv * 4 + 1) * 64 + lane) * 4) = acc1;
        *(f32x4*)(part + ((wv * 4 + 2) * 64 + lane) * 4) = acc2;
        *(f32x4*)(part + ((wv * 4 + 3) * 64 + lane) * 4) = acc3;
        __syncthreads();

        // reduce K-halves: hpf[g][b][c] = sum_kh part
        for (int eo = tid; eo < 2048; eo += 256) {
            int g2 = eo >> 9, b = (eo >> 4) & 31, c = eo & 15;
            int m = b >> 4, r = b & 3, l = ((b >> 2) & 3) * 16 + c;
            float v = part[(((m * 2 + 0) * 4 + g2) * 64 + l) * 4 + r]
                    + part[(((m * 2 + 1) * 4 + g2) * 64 + l) * 4 + r];
            hpf[eo] = v;
        }
        __syncthreads();

        // ---- gates: waves 0/1, thread owns (b, 4 consecutive cols) ----
        if (tid < 128) {
            const int b = tid >> 2, c4 = (tid & 3) * 4;
            const int gc0 = j0 + c4;
            float hn[4];
            u64 hpack = 0;
#pragma unroll
            for (int j = 0; j < 4; ++j) {
                const int e = b * 16 + c4 + j;
                float pr  = hpf[e];
                float pz  = hpf[512 + e];
                float pxn = hpf[1024 + e];
                float phn = hpf[1536 + e];
                float r = 1.f / (1.f + __expf(-(pr + br_[j])));
                float z = 1.f / (1.f + __expf(-(pz + bz_[j])));
                float na = pxn + bxn_[j] + r * (phn + bhn_[j]);
                float e2 = __expf(-2.f * na);
                float n = (1.f - e2) / (1.f + e2);      // tanh(na)
                float hprev = hloc[e];
                float h = (1.f - z) * n + z * hprev;
                hloc[e] = h;
                hn[j] = h;
                hpack |= (u64)f2bf(h) << (16 * j);
            }
            coh_store8((u64*)((unsigned short*)hb[(t + 1) & 1] + (size_t)b * 1024 + gc0), hpack);
            if (lay == 0)
                coh_store8((u64*)(y0b + ((size_t)t * NB + b) * 1024 + gc0), hpack);

            // per-wave drain of the coherent stores, then publish this half's flag
            asm volatile("s_waitcnt vmcnt(0)" ::: "memory");
            if ((tid & 63) == 0)
                __hip_atomic_store(pub, t + 1, __ATOMIC_RELAXED, __HIP_MEMORY_SCOPE_AGENT);

            // non-consumed outputs go out AFTER the publish (off the critical path)
            if (lay == 1) {
                float4 o4; o4.x = hn[0]; o4.y = hn[1]; o4.z = hn[2]; o4.w = hn[3];
                *(float4*)&out[((size_t)b * NT + t) * 1024 + gc0] = o4;
            }
            if (t == NT - 1) {
                float4 o4; o4.x = hn[0]; o4.y = hn[1]; o4.z = hn[2]; o4.w = hn[3];
                *(float4*)&out[(size_t)NB * NT * 1024 + (size_t)lay * NB * NH + (size_t)b * 1024 + gc0] = o4;
            }
        }
        // no block-wide barrier: next step's __syncthreads (after part store)
        // provides the intra-WG rendezvous; cross-WG ordering is via flags.
    }
}

extern "C" void kernel_launch(void* const* d_in, const int* in_sizes, int n_in,
                              void* d_out, int out_size, void* d_ws, size_t ws_size,
                              hipStream_t stream) {
    (void)in_sizes; (void)n_in; (void)out_size; (void)ws_size;

    const float* x     = (const float*)d_in[0];
    const float* hid   = (const float*)d_in[1];
    const float* w_ih0 = (const float*)d_in[2];
    const float* w_hh0 = (const float*)d_in[3];
    const float* b_ih0 = (const float*)d_in[4];
    const float* b_hh0 = (const float*)d_in[5];
    const float* w_ih1 = (const float*)d_in[6];
    const float* w_hh1 = (const float*)d_in[7];
    const float* b_ih1 = (const float*)d_in[8];
    const float* b_hh1 = (const float*)d_in[9];
    float* out = (float*)d_out;

    char* ws = (char*)d_ws;
    size_t off = 0;
    auto alloc = [&](size_t bytes) -> void* {
        void* p = ws + off;
        off += (bytes + 255) & ~(size_t)255;
        return p;
    };

    unsigned short* xtb   = (unsigned short*)alloc((size_t)NT * NB * 1024 * 2);
    unsigned short* y0b   = (unsigned short*)alloc((size_t)NT * NB * 1024 * 2);
    unsigned short* wih0b = (unsigned short*)alloc((size_t)G3 * 1024 * 2);
    unsigned short* whh0b = (unsigned short*)alloc((size_t)G3 * 1024 * 2);
    unsigned short* wih1b = (unsigned short*)alloc((size_t)G3 * 1024 * 2);
    unsigned short* whh1b = (unsigned short*)alloc((size_t)G3 * 1024 * 2);
    unsigned short* hb0[2]; unsigned short* hb1[2];
    for (int i = 0; i < 2; i++) hb0[i] = (unsigned short*)alloc(NB * NH * 2);
    for (int i = 0; i < 2; i++) hb1[i] = (unsigned short*)alloc(NB * NH * 2);
    int* flags = (int*)alloc(2 * 2 * 64 * sizeof(int));   // packed: [layer][half][64]

    // --- conversions / init ---
    txp_x<<<2048, 256, 0, stream>>>((const float4*)x, (us4*)xtb);
    cvt_bf16_v4<<<512, 256, 0, stream>>>((const float4*)w_ih0, (us4*)wih0b, G3 * 1024 / 4);
    cvt_bf16_v4<<<512, 256, 0, stream>>>((const float4*)w_hh0, (us4*)whh0b, G3 * 1024 / 4);
    cvt_bf16_v4<<<512, 256, 0, stream>>>((const float4*)w_ih1, (us4*)wih1b, G3 * 1024 / 4);
    cvt_bf16_v4<<<512, 256, 0, stream>>>((const float4*)w_hh1, (us4*)whh1b, G3 * 1024 / 4);
    init_h<<<NB * NH / 256, 256, 0, stream>>>(hid, hb0[0], hb1[0]);
    hipMemsetAsync(flags, 0, 2 * 2 * 64 * sizeof(int), stream);

    // --- persistent recurrence (both layers, wavefront-pipelined) ---
    (void)hipFuncSetAttribute((const void*)gru_persistent,
                              hipFuncAttributeMaxDynamicSharedMemorySize, PK_LDS);
    gru_persistent<<<NWG, 256, PK_LDS, stream>>>(
        xtb, y0b, wih0b, whh0b, wih1b, whh1b,
        b_ih0, b_hh0, b_ih1, b_hh1, hid,
        hb0[0], hb0[1], hb1[0], hb1[1],
        out, flags);
}